// Round 1
// baseline (1002.368 us; speedup 1.0000x reference)
//
#include <hip/hip_runtime.h>

#define N_IN  32768
#define K_EMB 4096
#define D_DIM 256

#define BN 128
#define BK 128
#define BD 32
#define LDP 132   // 128 + 4 pad: keeps 16B alignment for b128 LDS reads, breaks worst bank conflicts

// ---- workspace layout (bytes) ----
// wsq        : [0,      16384)    float[4096]
// cval       : [16384,  278528)   float[2][32768]
// cidx       : [278528, 540672)   int[2][32768]
// counts     : [540672, 557056)   int[4096]
// loss_slots : [557056, 557312)   float[64]
#define WS_WSQ    0
#define WS_CVAL   16384
#define WS_CIDX   278528
#define WS_COUNTS 540672
#define WS_LOSS   557056

// ---------------- kernel 1: wsq[k] = sum_d W[k][d]^2 ----------------
__global__ __launch_bounds__(256) void wsq_kernel(const float* __restrict__ W,
                                                  float* __restrict__ wsq)
{
    const int lane = threadIdx.x & 63;
    const int k = blockIdx.x * 4 + (threadIdx.x >> 6);
    float4 v = reinterpret_cast<const float4*>(W + (size_t)k * D_DIM)[lane];
    float s = v.x * v.x + v.y * v.y + v.z * v.z + v.w * v.w;
#pragma unroll
    for (int off = 32; off; off >>= 1) s += __shfl_xor(s, off);
    if (lane == 0) wsq[k] = s;
}

// ---------------- kernel 2: distances + per-row argmin ----------------
// Block tile: 128 n-rows x 128 k-rows, 256 threads, 8x8 micro-tile/thread.
// grid.y splits K in halves (2048 each) -> 512 blocks -> ~2 blocks/CU.
// Discriminant: d_k = wsq[k] - 2 * dot(x,w_k)   (||x||^2 dropped: constant per row,
// and including it at fp32 would destroy the ~1e-3 winner gaps; see analysis).
__global__ __launch_bounds__(256) void dist_kernel(const float* __restrict__ X,
                                                   const float* __restrict__ W,
                                                   const float* __restrict__ wsq,
                                                   float* __restrict__ cval,
                                                   int*   __restrict__ cidx)
{
    __shared__ float xs[BD][LDP];  // transposed: xs[d][n]
    __shared__ float wsh[BD][LDP]; // transposed: wsh[d][k]

    const int tid = threadIdx.x;
    const int tn = tid >> 4;   // 0..15 -> owns rows nbase + tn*8 .. +7
    const int tk = tid & 15;   // 0..15 -> owns cols kb0 + tk*8 .. +7
    const int nbase  = blockIdx.x * BN;
    const int kstart = blockIdx.y * (K_EMB / 2);

    const int rb = tid >> 3;   // staging: row sub-index
    const int c4 = tid & 7;    // staging: which float4 within the 32-d chunk

    float bestv[8];
    int   besti[8];
#pragma unroll
    for (int i = 0; i < 8; i++) { bestv[i] = 3.4e38f; besti[i] = 0x7fffffff; }

    for (int kt = 0; kt < (K_EMB / 2) / BK; ++kt) {
        const int kb0 = kstart + kt * BK;
        float acc[8][8];
#pragma unroll
        for (int i = 0; i < 8; i++)
#pragma unroll
            for (int j = 0; j < 8; j++) acc[i][j] = 0.f;

        for (int d0 = 0; d0 < D_DIM; d0 += BD) {
            __syncthreads();   // protect previous chunk's readers
#pragma unroll
            for (int q = 0; q < 4; q++) {
                const int r = q * 32 + rb;
                float4 xv = *reinterpret_cast<const float4*>(
                    X + (size_t)(nbase + r) * D_DIM + d0 + c4 * 4);
                xs[c4 * 4 + 0][r] = xv.x; xs[c4 * 4 + 1][r] = xv.y;
                xs[c4 * 4 + 2][r] = xv.z; xs[c4 * 4 + 3][r] = xv.w;
                float4 wv = *reinterpret_cast<const float4*>(
                    W + (size_t)(kb0 + r) * D_DIM + d0 + c4 * 4);
                wsh[c4 * 4 + 0][r] = wv.x; wsh[c4 * 4 + 1][r] = wv.y;
                wsh[c4 * 4 + 2][r] = wv.z; wsh[c4 * 4 + 3][r] = wv.w;
            }
            __syncthreads();

#pragma unroll 4
            for (int d = 0; d < BD; ++d) {
                float4 a0 = *reinterpret_cast<const float4*>(&xs[d][tn * 8]);
                float4 a1 = *reinterpret_cast<const float4*>(&xs[d][tn * 8 + 4]);
                float4 b0 = *reinterpret_cast<const float4*>(&wsh[d][tk * 8]);
                float4 b1 = *reinterpret_cast<const float4*>(&wsh[d][tk * 8 + 4]);
                float a[8] = {a0.x, a0.y, a0.z, a0.w, a1.x, a1.y, a1.z, a1.w};
                float b[8] = {b0.x, b0.y, b0.z, b0.w, b1.x, b1.y, b1.z, b1.w};
#pragma unroll
                for (int i = 0; i < 8; i++)
#pragma unroll
                    for (int j = 0; j < 8; j++)
                        acc[i][j] = fmaf(a[i], b[j], acc[i][j]);
            }
        }

        // epilogue: discriminant + running argmin (j ascending => first-min kept)
        const int kb = kb0 + tk * 8;
#pragma unroll
        for (int j = 0; j < 8; j++) {
            const float wq = wsq[kb + j];
#pragma unroll
            for (int i = 0; i < 8; i++) {
                const float dist = fmaf(-2.f, acc[i][j], wq);
                if (dist < bestv[i]) { bestv[i] = dist; besti[i] = kb + j; }
            }
        }
    }

    // reduce (val,idx) across the 16 tk-threads (contiguous lanes within wave)
#pragma unroll
    for (int i = 0; i < 8; i++) {
#pragma unroll
        for (int off = 1; off < 16; off <<= 1) {
            float ov = __shfl_xor(bestv[i], off);
            int   oi = __shfl_xor(besti[i], off);
            if (ov < bestv[i] || (ov == bestv[i] && oi < besti[i])) {
                bestv[i] = ov; besti[i] = oi;
            }
        }
        if (tk == 0) {
            const int n = nbase + tn * 8 + i;
            cval[blockIdx.y * N_IN + n] = bestv[i];
            cidx[blockIdx.y * N_IN + n] = besti[i];
        }
    }
}

// ---------------- kernel 3: merge halves, gather, loss, histogram ----------------
__global__ __launch_bounds__(256) void gather_kernel(const float* __restrict__ X,
                                                     const float* __restrict__ W,
                                                     const float* __restrict__ cval,
                                                     const int*   __restrict__ cidx,
                                                     int*   __restrict__ counts,
                                                     float* __restrict__ loss_slots,
                                                     float* __restrict__ outq)
{
    const int lane = threadIdx.x & 63;
    const int wv   = threadIdx.x >> 6;
    const int n    = blockIdx.x * 4 + wv;

    const float v0 = cval[n],        v1 = cval[N_IN + n];
    const int   i0 = cidx[n],        i1 = cidx[N_IN + n];
    const int   idx = (v1 < v0 || (v1 == v0 && i1 < i0)) ? i1 : i0;

    if (lane == 0) atomicAdd(&counts[idx], 1);

    const float* wr = W + (size_t)idx * D_DIM;
    const float* xr = X + (size_t)n * D_DIM;
    float ls = 0.f;
#pragma unroll
    for (int q = 0; q < 4; q++) {
        const int d = q * 64 + lane;
        const float w = wr[d];
        const float x = xr[d];
        const float df = w - x;
        ls = fmaf(df, df, ls);
        outq[(size_t)n * D_DIM + d] = w;  // quantized_st == quantized (value-wise)
    }
#pragma unroll
    for (int off = 32; off; off >>= 1) ls += __shfl_xor(ls, off);

    __shared__ float part[4];
    if (lane == 0) part[wv] = ls;
    __syncthreads();
    if (threadIdx.x == 0)
        atomicAdd(&loss_slots[blockIdx.x & 63], part[0] + part[1] + part[2] + part[3]);
}

// ---------------- kernel 4: entropy / perplexity / loss finalize ----------------
__global__ __launch_bounds__(256) void finalize_kernel(const int* __restrict__ counts,
                                                       const float* __restrict__ loss_slots,
                                                       float* __restrict__ out)
{
    const int tid = threadIdx.x;
    float ent = 0.f;
    for (int k = tid; k < K_EMB; k += 256) {
        const float p = (float)counts[k] * (1.0f / (float)N_IN);
        ent += p * logf(p + 1e-10f);
    }
#pragma unroll
    for (int off = 32; off; off >>= 1) ent += __shfl_xor(ent, off);
    __shared__ float red[4];
    if ((tid & 63) == 0) red[tid >> 6] = ent;
    __syncthreads();
    if (tid == 0) {
        const float e = red[0] + red[1] + red[2] + red[3];
        float ls = 0.f;
        for (int i = 0; i < 64; i++) ls += loss_slots[i];
        out[0] = 1.25f * ls / ((float)N_IN * (float)D_DIM);  // q_loss + 0.25*e_loss
        out[1 + (size_t)N_IN * D_DIM] = expf(-e);
    }
}

extern "C" void kernel_launch(void* const* d_in, const int* in_sizes, int n_in,
                              void* d_out, int out_size, void* d_ws, size_t ws_size,
                              hipStream_t stream)
{
    const float* X = (const float*)d_in[0];
    const float* W = (const float*)d_in[1];
    float* out = (float*)d_out;
    char*  ws  = (char*)d_ws;

    float* wsq        = (float*)(ws + WS_WSQ);
    float* cval       = (float*)(ws + WS_CVAL);
    int*   cidx       = (int*)  (ws + WS_CIDX);
    int*   counts     = (int*)  (ws + WS_COUNTS);
    float* loss_slots = (float*)(ws + WS_LOSS);

    // counts + loss_slots are contiguous: one memset (ws is re-poisoned before each launch)
    hipMemsetAsync(counts, 0, 16384 + 256, stream);

    wsq_kernel<<<K_EMB / 4, 256, 0, stream>>>(W, wsq);
    dist_kernel<<<dim3(N_IN / BN, 2), 256, 0, stream>>>(X, W, wsq, cval, cidx);
    gather_kernel<<<N_IN / 4, 256, 0, stream>>>(X, W, cval, cidx, counts, loss_slots, out + 1);
    finalize_kernel<<<1, 256, 0, stream>>>(counts, loss_slots, out);
}

// Round 2
// 290.823 us; speedup vs baseline: 3.4467x; 3.4467x over previous
//
#include <hip/hip_runtime.h>
#include <hip/hip_bf16.h>

#define M_IN  32768   // GEMM M: input rows
#define K_EMB 4096    // GEMM N: codewords
#define D_DIM 256     // GEMM K: reduction dim

#define BM 128
#define BN 128
#define BK 64

// ---- ws layout (bytes), total 295 KB (< 557 KB proven safe in round 1) ----
#define WS_HWSQ   0         // float[4096]   : 0.5*||w_k||^2
#define WS_PACKS  16384     // u64[32768]    : per-row argmin pack (distbits<<32 | idx)
#define WS_COUNTS 278528    // int[4096]
#define WS_LOSS   294912    // float[64]

// bf16 staging lives inside d_out's quantized region (overwritten by merge_kernel):
//   Xb @ byte 16 (16.78 MB), Wb @ byte 16+16777216 (2 MB); region ends < 18.9 MB < 33.5 MB.

using f32x4  = __attribute__((ext_vector_type(4))) float;
using bf16x8 = __attribute__((ext_vector_type(8))) short;

#define GLL16(g, l) __builtin_amdgcn_global_load_lds( \
    (const __attribute__((address_space(1))) void*)(g), \
    (__attribute__((address_space(3))) void*)(l), 16, 0, 0)

__device__ __forceinline__ unsigned short bf16_rtn(float f) {
    __hip_bfloat16 h = __float2bfloat16(f);  // RTN-even
    return *reinterpret_cast<unsigned short*>(&h);
}

// ---------------- conv X: f32 -> bf16, 8 elems/thread ----------------
__global__ __launch_bounds__(256) void convx_kernel(const float* __restrict__ X,
                                                    unsigned short* __restrict__ Xb)
{
    const int gid = blockIdx.x * 256 + threadIdx.x;
    const float4 a = ((const float4*)X)[(size_t)gid * 2];
    const float4 b = ((const float4*)X)[(size_t)gid * 2 + 1];
    union { unsigned short u[8]; uint4 v; } p;
    p.u[0] = bf16_rtn(a.x); p.u[1] = bf16_rtn(a.y);
    p.u[2] = bf16_rtn(a.z); p.u[3] = bf16_rtn(a.w);
    p.u[4] = bf16_rtn(b.x); p.u[5] = bf16_rtn(b.y);
    p.u[6] = bf16_rtn(b.z); p.u[7] = bf16_rtn(b.w);
    ((uint4*)Xb)[gid] = p.v;
}

// ---------------- conv W: f32 -> bf16 + halfwsq ----------------
__global__ __launch_bounds__(256) void convw_kernel(const float* __restrict__ W,
                                                    unsigned short* __restrict__ Wb,
                                                    float* __restrict__ hwsq)
{
    const int l = threadIdx.x & 63;
    const int k = blockIdx.x * 4 + (threadIdx.x >> 6);
    float4 v = ((const float4*)(W + (size_t)k * D_DIM))[l];
    float s = v.x * v.x + v.y * v.y + v.z * v.z + v.w * v.w;
    union { unsigned short u[4]; uint2 q; } p;
    p.u[0] = bf16_rtn(v.x); p.u[1] = bf16_rtn(v.y);
    p.u[2] = bf16_rtn(v.z); p.u[3] = bf16_rtn(v.w);
    ((uint2*)(Wb + (size_t)k * D_DIM))[l] = p.q;
#pragma unroll
    for (int off = 32; off; off >>= 1) s += __shfl_xor(s, off);
    if (l == 0) hwsq[k] = 0.5f * s;
}

// ---------------- dist: bf16 MFMA GEMM + fused argmin epilogue ----------------
// C[m][n] = dot(X[m], W[n]); proxy dist = hwsq[n] - C. 128x128 tile, 4 waves (2x2),
// each wave 64x64 via 4x4 frags of mfma_f32_16x16x32_bf16. NT layout: A-frag and
// B-frag both read 8 contiguous bf16 from row-major [row][64] LDS tiles.
__global__ __launch_bounds__(256) void dist_kernel(const unsigned short* __restrict__ Xb,
                                                   const unsigned short* __restrict__ Wb,
                                                   const float* __restrict__ hwsq,
                                                   unsigned long long* __restrict__ packs)
{
    __shared__ unsigned short As[BM * BK];   // [row][64] bf16, 16 KB
    __shared__ unsigned short Bs[BN * BK];   // 16 KB
    __shared__ unsigned long long merge_lds[BM][2];

    const int t  = threadIdx.x;
    const int l  = t & 63;
    const int w  = t >> 6;
    const int wm = w >> 1, wn = w & 1;
    const int m0    = blockIdx.y * BM;
    const int nbase = blockIdx.x * BN;

    f32x4 acc[4][4];
#pragma unroll
    for (int mi = 0; mi < 4; mi++)
#pragma unroll
        for (int nj = 0; nj < 4; nj++) acc[mi][nj] = (f32x4){0.f, 0.f, 0.f, 0.f};

    const int srow = t >> 3;        // staging: row-in-32-group
    const int schk = t & 7;         // staging: 16B chunk in row

    for (int kt = 0; kt < D_DIM / BK; ++kt) {
        __syncthreads();   // previous tile's readers done
#pragma unroll
        for (int i = 0; i < 4; ++i) {
            const unsigned short* ga = Xb + (size_t)(m0 + i * 32 + srow) * D_DIM
                                          + kt * BK + schk * 8;
            GLL16(ga, (char*)As + i * 4096 + w * 1024);
            const unsigned short* gb = Wb + (size_t)(nbase + i * 32 + srow) * D_DIM
                                          + kt * BK + schk * 8;
            GLL16(gb, (char*)Bs + i * 4096 + w * 1024);
        }
        __syncthreads();   // vmcnt(0) drained before barrier by compiler

#pragma unroll
        for (int kk = 0; kk < 2; ++kk) {
            bf16x8 af[4], bfr[4];
#pragma unroll
            for (int mi = 0; mi < 4; mi++)
                af[mi] = *(const bf16x8*)((const char*)As
                         + (wm * 64 + mi * 16 + (l & 15)) * 128 + kk * 64 + (l >> 4) * 16);
#pragma unroll
            for (int nj = 0; nj < 4; nj++)
                bfr[nj] = *(const bf16x8*)((const char*)Bs
                         + (wn * 64 + nj * 16 + (l & 15)) * 128 + kk * 64 + (l >> 4) * 16);
#pragma unroll
            for (int mi = 0; mi < 4; mi++)
#pragma unroll
                for (int nj = 0; nj < 4; nj++)
                    acc[mi][nj] = __builtin_amdgcn_mfma_f32_16x16x32_bf16(
                        af[mi], bfr[nj], acc[mi][nj], 0, 0, 0);
        }
    }

    // epilogue: per-row argmin. C/D layout: col = l&15, row = (l>>4)*4 + reg (m89).
    float hw[4];
#pragma unroll
    for (int nj = 0; nj < 4; nj++)
        hw[nj] = hwsq[nbase + wn * 64 + nj * 16 + (l & 15)];

#pragma unroll
    for (int mi = 0; mi < 4; mi++) {
#pragma unroll
        for (int r = 0; r < 4; r++) {
            float bv = 3.4e38f; int bi = 0;
#pragma unroll
            for (int nj = 0; nj < 4; nj++) {
                const float v = hw[nj] - acc[mi][nj][r];
                const int idx = nbase + wn * 64 + nj * 16 + (l & 15);
                if (v < bv) { bv = v; bi = idx; }   // nj ascending -> lowest idx on tie
            }
            // +1.0f bias -> positive float -> bits monotone; idx in low bits = tiebreak-low
            unsigned long long pk =
                ((unsigned long long)__float_as_uint(bv + 1.0f) << 32) | (unsigned)bi;
#pragma unroll
            for (int off = 1; off < 16; off <<= 1) {
                const unsigned long long o = __shfl_xor(pk, off);
                if (o < pk) pk = o;
            }
            if ((l & 15) == 0)
                merge_lds[wm * 64 + mi * 16 + (l >> 4) * 4 + r][wn] = pk;
        }
    }
    __syncthreads();
    if (t < BM) {
        const unsigned long long p0 = merge_lds[t][0], p1 = merge_lds[t][1];
        atomicMin(&packs[m0 + t], p0 < p1 ? p0 : p1);
    }
}

// ---------------- merge: unpack idx, gather W row, loss, counts ----------------
__global__ __launch_bounds__(256) void merge_kernel(const float* __restrict__ X,
                                                    const float* __restrict__ W,
                                                    const unsigned long long* __restrict__ packs,
                                                    int* __restrict__ counts,
                                                    float* __restrict__ loss_slots,
                                                    float* __restrict__ outq)
{
    const int l  = threadIdx.x & 63;
    const int wv = threadIdx.x >> 6;
    const int n  = blockIdx.x * 4 + wv;

    const int idx = (int)(unsigned)(packs[n] & 0xffffffffull);
    if (l == 0) atomicAdd(&counts[idx], 1);

    const float4 w4 = ((const float4*)(W + (size_t)idx * D_DIM))[l];
    const float4 x4 = ((const float4*)(X + (size_t)n   * D_DIM))[l];
    float* orow = outq + (size_t)n * D_DIM + l * 4;  // outq = out+1: only 4B-aligned -> scalar stores
    orow[0] = w4.x; orow[1] = w4.y; orow[2] = w4.z; orow[3] = w4.w;

    const float d0 = w4.x - x4.x, d1 = w4.y - x4.y, d2 = w4.z - x4.z, d3 = w4.w - x4.w;
    float ls = fmaf(d0, d0, fmaf(d1, d1, fmaf(d2, d2, d3 * d3)));
#pragma unroll
    for (int off = 32; off; off >>= 1) ls += __shfl_xor(ls, off);

    __shared__ float part[4];
    if (l == 0) part[wv] = ls;
    __syncthreads();
    if (threadIdx.x == 0)
        atomicAdd(&loss_slots[blockIdx.x & 63], part[0] + part[1] + part[2] + part[3]);
}

// ---------------- finalize ----------------
__global__ __launch_bounds__(256) void finalize_kernel(const int* __restrict__ counts,
                                                       const float* __restrict__ loss_slots,
                                                       float* __restrict__ out)
{
    const int tid = threadIdx.x;
    float ent = 0.f;
    for (int k = tid; k < K_EMB; k += 256) {
        const float p = (float)counts[k] * (1.0f / (float)M_IN);
        ent += p * logf(p + 1e-10f);
    }
#pragma unroll
    for (int off = 32; off; off >>= 1) ent += __shfl_xor(ent, off);
    __shared__ float red[4];
    if ((tid & 63) == 0) red[tid >> 6] = ent;
    __syncthreads();
    if (tid == 0) {
        const float e = red[0] + red[1] + red[2] + red[3];
        float ls = 0.f;
        for (int i = 0; i < 64; i++) ls += loss_slots[i];
        out[0] = 1.25f * ls / ((float)M_IN * (float)D_DIM);
        out[1 + (size_t)M_IN * D_DIM] = expf(-e);
    }
}

extern "C" void kernel_launch(void* const* d_in, const int* in_sizes, int n_in,
                              void* d_out, int out_size, void* d_ws, size_t ws_size,
                              hipStream_t stream)
{
    const float* X = (const float*)d_in[0];
    const float* W = (const float*)d_in[1];
    float* out = (float*)d_out;
    char*  ws  = (char*)d_ws;

    float* hwsq                = (float*)(ws + WS_HWSQ);
    unsigned long long* packs  = (unsigned long long*)(ws + WS_PACKS);
    int*   counts              = (int*)(ws + WS_COUNTS);
    float* loss_slots          = (float*)(ws + WS_LOSS);

    // bf16 staging inside d_out (fully overwritten by merge/finalize afterwards)
    unsigned short* Xb = (unsigned short*)((char*)d_out + 16);
    unsigned short* Wb = (unsigned short*)((char*)d_out + 16 + 16777216);

    hipMemsetAsync(ws + WS_PACKS, 0xFF, 262144, stream);          // packs = +inf
    hipMemsetAsync(ws + WS_COUNTS, 0, 16384 + 256, stream);       // counts + loss_slots

    convx_kernel<<<(M_IN * D_DIM / 8) / 256, 256, 0, stream>>>(X, Xb);
    convw_kernel<<<K_EMB / 4, 256, 0, stream>>>(W, Wb, hwsq);
    dist_kernel<<<dim3(K_EMB / BN, M_IN / BM), 256, 0, stream>>>(Xb, Wb, hwsq, packs);
    merge_kernel<<<M_IN / 4, 256, 0, stream>>>(X, W, packs, counts, loss_slots, out + 1);
    finalize_kernel<<<1, 256, 0, stream>>>(counts, loss_slots, out);
}